// Round 1
// baseline (615.952 us; speedup 1.0000x reference)
//
#include <hip/hip_runtime.h>

#define CC 128
#define HH 128
#define WW 128
#define DH 64
#define DW 64
#define LTOT 4096          // DH*DW patches / fg positions
#define K0S 384            // 3*128 split-concat K for the pixel-pair GEMM
#define K2 2048            // CC*4*4
#define SCALE_F 10.0f
#define IMG ((size_t)CC * HH * WW)

typedef __attribute__((ext_vector_type(8))) short short8;
typedef __attribute__((ext_vector_type(4))) float f32x4;

// ---- pointer-pack structs (batch-merged prep via blockIdx.z) ----
struct Prep4 { const float* src[4]; unsigned short* dst[4]; float* ssq[4]; int lo[4]; };
struct PtrN2 { const float* ssq[2]; float* invn[2]; float* mmv[2]; };
struct PtrR2 { const float* src[2]; unsigned short* dst[2]; };

// ---- bf16 helpers (RNE) ----
__device__ __forceinline__ unsigned short f2bf(float x) {
    union { float f; unsigned u; } v; v.f = x;
    unsigned r = v.u + 0x7fffu + ((v.u >> 16) & 1u);
    return (unsigned short)(r >> 16);
}
__device__ __forceinline__ float bf2f(unsigned short b) {
    union { unsigned u; float f; } v; v.u = ((unsigned)b) << 16;
    return v.f;
}

#define GLDS16(g, l) __builtin_amdgcn_global_load_lds( \
    (const __attribute__((address_space(1))) void*)(g), \
    (__attribute__((address_space(3))) void*)(l), 16, 0, 0)

// ---------------- downsample (::2) + fp32->bf16 split + (for b) fused ssq reduce ----------------
// b gets [hi, lo, hi], f gets [hi, hi, lo]  =>  products sum to hi*hi + lo*hi + hi*lo
__global__ __launch_bounds__(128) void split_ds_kernel(Prep4 P) {
    __shared__ float partial[2];
    int z = blockIdx.z;
    const float* __restrict__ src = P.src[z];
    unsigned short* __restrict__ dst = P.dst[z];
    int lo_in_seg1 = P.lo[z];
    int n = blockIdx.x;          // 4096 pixels
    int c = threadIdx.x;         // 128 channels
    int ny = n >> 6, nx = n & 63;
    float v = src[((size_t)c * HH + 2 * ny) * WW + 2 * nx];
    unsigned short hi = f2bf(v);
    unsigned short lo = f2bf(v - bf2f(hi));
    unsigned short* drow = dst + (size_t)n * K0S;
    drow[c]       = hi;
    drow[128 + c] = lo_in_seg1 ? lo : hi;
    drow[256 + c] = lo_in_seg1 ? hi : lo;

    float* ssq = P.ssq[z];
    if (ssq) {                   // b images only: per-pixel channel sum of squares
        float s2 = v * v;
#pragma unroll
        for (int o = 32; o; o >>= 1) s2 += __shfl_xor(s2, o);
        if ((threadIdx.x & 63) == 0) partial[threadIdx.x >> 6] = s2;
        __syncthreads();
        if (threadIdx.x == 0) ssq[n] = partial[0] + partial[1];
    }
}

// ---------------- raw 4x4 stride-2 patches of full-res b, transposed: dst[m2][p] bf16 ----------------
__global__ __launch_bounds__(256) void im2col_rawt_kernel(PtrR2 P) {
    int z = blockIdx.z;
    const float* __restrict__ src = P.src[z];
    unsigned short* __restrict__ dst = P.dst[z];
    int idx = blockIdx.x * 256 + threadIdx.x;   // K2*LTOT threads, p fastest
    int p = idx & (LTOT - 1);
    int m = idx >> 12;
    int px = p & 63, py = p >> 6;
    int ke = m & 3, kd = (m >> 2) & 3, c = m >> 4;
    int yy = 2 * py - 1 + kd, xx = 2 * px - 1 + ke;
    float v = 0.f;
    if (yy >= 0 && yy < HH && xx >= 0 && xx < WW)
        v = src[((size_t)c * HH + yy) * WW + xx];
    dst[idx] = f2bf(v);
}

// ---------------- patch inverse norm + mask gate ----------------
__global__ void norm_mm_kernel(PtrN2 P, const float* __restrict__ mask) {
    int z = blockIdx.z;
    const float* __restrict__ ssq = P.ssq[z];
    float* __restrict__ inv_norm = P.invn[z];
    float* __restrict__ mmv = P.mmv[z];
    int p = blockIdx.x * blockDim.x + threadIdx.x;     // 4096
    int px = p & 63, py = p >> 6;
    float s = 0.f, ms = 0.f;
    for (int di = -1; di <= 1; ++di)
        for (int dj = -1; dj <= 1; ++dj) {
            int y = py + di, x = px + dj;
            if (y >= 0 && y < DH && x >= 0 && x < DW) {
                s += ssq[y * 64 + x];
                ms += mask[(size_t)(2 * y) * WW + 2 * x];
            }
        }
    float n = sqrtf(s);
    if (n < 1e-4f) n = 1e-4f;
    inv_norm[p] = 1.f / n;
    mmv[p] = (ms == 0.f) ? 1.f : 0.f;
}

// ---------------- bf16 MFMA GEMM, BK=64, hoisted running pointers, XOR swizzle ----------------
// A[M][K], B[N][K], C[M][N] fp32. 128x128 tile, 4 waves 2x2, each 4x4x(2 k-slab) MFMA 16x16x32.
// LDS rows of 128B = 8 chunks of 16B; chunk slot s of row m holds global chunk s ^ (m&7).
__global__ __launch_bounds__(256) void gemm_mfma(
    const unsigned short* __restrict__ Aop, const unsigned short* __restrict__ Bop,
    float* __restrict__ C, int M, int N, int K)
{
    __shared__ short As[128 * 64];
    __shared__ short Bs[128 * 64];
    int tid = threadIdx.x;
    int wave = tid >> 6, lane = tid & 63;
    int wm = (wave >> 1) * 64;
    int wn = (wave & 1) * 64;
    int bm = blockIdx.y * 128, bn = blockIdx.x * 128;

    int rowS = wave * 32;              // wave stages rows [rowS, rowS+32)
    int lrow8 = lane >> 3;             // 0..7 (row within 8-row staging group)
    int gchunk = ((lane & 7) ^ lrow8) * 8;   // swizzled global k-offset (shorts)

    f32x4 acc[4][4] = {};

    int quad = lane >> 4;              // 0..3
    int r16 = lane & 15;
    int pc0 = ((quad)     ^ (r16 & 7)) * 8;  // physical chunk of k-slab 0
    int pc1 = ((4 + quad) ^ (r16 & 7)) * 8;  // physical chunk of k-slab 1

    // hoisted running pointers (k0-invariant base; += 64 shorts per iter)
    const unsigned short* ap0 = Aop + (size_t)(bm + rowS +  0 + lrow8) * K + gchunk;
    const unsigned short* ap1 = Aop + (size_t)(bm + rowS +  8 + lrow8) * K + gchunk;
    const unsigned short* ap2 = Aop + (size_t)(bm + rowS + 16 + lrow8) * K + gchunk;
    const unsigned short* ap3 = Aop + (size_t)(bm + rowS + 24 + lrow8) * K + gchunk;
    const unsigned short* bp0 = Bop + (size_t)(bn + rowS +  0 + lrow8) * K + gchunk;
    const unsigned short* bp1 = Bop + (size_t)(bn + rowS +  8 + lrow8) * K + gchunk;
    const unsigned short* bp2 = Bop + (size_t)(bn + rowS + 16 + lrow8) * K + gchunk;
    const unsigned short* bp3 = Bop + (size_t)(bn + rowS + 24 + lrow8) * K + gchunk;
    short* lA = As + rowS * 64;        // wave-uniform LDS bases
    short* lB = Bs + rowS * 64;

    for (int k0 = 0; k0 < K; k0 += 64) {
        GLDS16(ap0, lA);            GLDS16(ap1, lA + 8 * 64);
        GLDS16(ap2, lA + 16 * 64);  GLDS16(ap3, lA + 24 * 64);
        GLDS16(bp0, lB);            GLDS16(bp1, lB + 8 * 64);
        GLDS16(bp2, lB + 16 * 64);  GLDS16(bp3, lB + 24 * 64);
        ap0 += 64; ap1 += 64; ap2 += 64; ap3 += 64;
        bp0 += 64; bp1 += 64; bp2 += 64; bp3 += 64;
        __syncthreads();

        short8 a0[4], b0[4], a1[4], b1[4];
#pragma unroll
        for (int i = 0; i < 4; ++i) {
            a0[i] = *(const short8*)&As[(wm + i * 16 + r16) * 64 + pc0];
            b0[i] = *(const short8*)&Bs[(wn + i * 16 + r16) * 64 + pc0];
            a1[i] = *(const short8*)&As[(wm + i * 16 + r16) * 64 + pc1];
            b1[i] = *(const short8*)&Bs[(wn + i * 16 + r16) * 64 + pc1];
        }
#pragma unroll
        for (int i = 0; i < 4; ++i)
#pragma unroll
            for (int j = 0; j < 4; ++j) {
                acc[i][j] = __builtin_amdgcn_mfma_f32_16x16x32_bf16(a0[i], b0[j], acc[i][j], 0, 0, 0);
                acc[i][j] = __builtin_amdgcn_mfma_f32_16x16x32_bf16(a1[i], b1[j], acc[i][j], 0, 0, 0);
            }
        __syncthreads();
    }

    int col = lane & 15, rq = (lane >> 4) * 4;
#pragma unroll
    for (int i = 0; i < 4; ++i) {
#pragma unroll
        for (int r = 0; r < 4; ++r) {
            int m = bm + wm + i * 16 + rq + r;
#pragma unroll
            for (int j = 0; j < 4; ++j)
                C[(size_t)m * N + bn + wn + j * 16 + col] = acc[i][j][r];
        }
    }
}

// ---------------- 9-tap patch stencil: S[q][p] = invn[p] * sum_{u,v} C[q+δ][p+δ], δ=64du+dv ----------------
// XCD swizzle: blocks with equal (blk&7) share an XCD and own a contiguous 512-row q range.
__global__ __launch_bounds__(256) void stencil_norm_kernel(
    const float* __restrict__ C, const float* __restrict__ invn,
    float* __restrict__ Sout)
{
    int blk = blockIdx.x;
    int q = ((blk & 7) << 9) | (blk >> 3);
    int t = threadIdx.x;
    int qy = q >> 6, qx = q & 63;
    int px = t & 63;
    int py0 = t >> 6;
    float acc[16] = {};
#pragma unroll
    for (int du = -1; du <= 1; ++du) {
        if (qy + du < 0 || qy + du > 63) continue;
#pragma unroll
        for (int dv = -1; dv <= 1; ++dv) {
            if (qx + dv < 0 || qx + dv > 63) continue;
            if (px + dv < 0 || px + dv > 63) continue;
            const float* row = C + (size_t)(q + 64 * du + dv) * LTOT + 64 * du + dv;
#pragma unroll
            for (int i = 0; i < 16; ++i) {
                int py = py0 + 4 * i;
                if (py + du < 0 || py + du > 63) continue;
                acc[i] += row[t + 256 * i];
            }
        }
    }
    float* orow = Sout + (size_t)q * LTOT;
#pragma unroll
    for (int i = 0; i < 16; ++i)
        orow[t + 256 * i] = acc[i] * invn[t + 256 * i];
}

// ---------------- fused: (fuse2 o fuse1) 9-tap diagonal stencil + row softmax + bf16 write ----------------
// R12: the launch_bounds(256,4) register-budget grant did NOT take — PMC showed VGPR_Count=24,
// i.e. the compiler STILL rematerialized the whole 144-gather stencil in each of the
// max / exp-sum / write passes (S read ~3x from L2: ~1.8 GB/dispatch, VALU cycles ~33 µs,
// matching VALUBusy 35.5% x 92.4 µs). Fix: materialize v[16] in a private LDS slab
// vbuf[16][256] (16 KB, stride-1 conflict-free, each slot touched by exactly one thread ->
// no extra barriers). Compute pass writes vbuf; exp pass overwrites it with exp(v-gmx);
// write pass reads it back. The compiler cannot rematerialize an LDS read into S re-reads.
// mmv (16 KB, L1-resident) is re-read in the write pass instead of keeping m[16] live.
__global__ __launch_bounds__(256) void fused_conv_softmax_kernel(
    const float* __restrict__ S, const float* __restrict__ mmv,
    unsigned short* __restrict__ S16)
{
    __shared__ float vbuf[16 * 256];    // per-thread v values; slot (i<<8)+t is private to thread t
    __shared__ float redmax[4];
    __shared__ float redsum[4];
    int blk = blockIdx.x;
    int q = ((blk & 7) << 9) | (blk >> 3);
    int t = threadIdx.x;
    int lane = t & 63, wid = t >> 6;

    int rbase = ((q & 63) << 6) | (q >> 6);     // swap(q)
    int rrs[3];
    bool rok[3];
#pragma unroll
    for (int j = 0; j < 3; ++j) {
        int r2 = rbase + (j - 1);
        rok[j] = (r2 >= 0) && (r2 < LTOT);
        rrs[j] = ((r2 & 63) << 6) | ((r2 >> 6) & 63);   // swap(r2)
    }

    float mx = -3.0e38f;
#pragma unroll
    for (int i = 0; i < 16; ++i) {
        int c = t + (i << 8);                   // column p, 0..4095
        int cbase = ((c & 63) << 6) | (c >> 6); // swap(c)
        float s = 0.f;
#pragma unroll
        for (int j = 0; j < 3; ++j) {           // d2 = j-1 (fuse2 order)
            if (!rok[j]) continue;
            int c2 = cbase + (j - 1);
            if (c2 < 0 || c2 >= LTOT) continue;
            int cc = ((c2 & 63) << 6) | (c2 >> 6);  // swap(c2); interior: c + 64*d2
            int rr = rrs[j];
            float tsum = 0.f;
#pragma unroll
            for (int d1 = -1; d1 <= 1; ++d1) {  // fuse1 order
                int a = rr + d1, bcol = cc + d1;
                if (a >= 0 && a < LTOT && bcol >= 0 && bcol < LTOT)
                    tsum += S[(size_t)a * LTOT + bcol];
            }
            s += tsum;
        }
        float val = s * mmv[c] * SCALE_F;
        vbuf[(i << 8) + t] = val;
        mx = fmaxf(mx, val);
    }

#pragma unroll
    for (int o = 32; o; o >>= 1) mx = fmaxf(mx, __shfl_xor(mx, o));
    if (lane == 0) redmax[wid] = mx;
    __syncthreads();
    float gmx = fmaxf(fmaxf(redmax[0], redmax[1]), fmaxf(redmax[2], redmax[3]));

    float s = 0.f;
#pragma unroll
    for (int i = 0; i < 16; ++i) {
        float e = __expf(vbuf[(i << 8) + t] - gmx);
        vbuf[(i << 8) + t] = e;
        s += e;
    }
#pragma unroll
    for (int o = 32; o; o >>= 1) s += __shfl_xor(s, o);
    if (lane == 0) redsum[wid] = s;
    __syncthreads();
    float inv = 1.f / (redsum[0] + redsum[1] + redsum[2] + redsum[3]);

    unsigned short* orow = S16 + (size_t)q * LTOT;
#pragma unroll
    for (int i = 0; i < 16; ++i) {
        int c = t + (i << 8);
        orow[c] = f2bf(vbuf[(i << 8) + t] * inv * mmv[c]);
    }
}

// ---------------- overlap-add of weighted 4x4 patches (stride 2), /4 ----------------
// C2t is TRANSPOSED: [m2][q] = [(c,kd,ke)][oy*64+ox] -> taps contiguous across threads (x->ox).
__global__ void output_kernel(const float* __restrict__ C2t, float* __restrict__ out) {
    int idx = blockIdx.x * blockDim.x + threadIdx.x;   // CC*HH*WW
    int x = idx & 127;
    int y = (idx >> 7) & 127;
    int c = idx >> 14;
    int oylo = max(0, (y - 1) >> 1), oyhi = min(63, (y + 1) >> 1);
    int oxlo = max(0, (x - 1) >> 1), oxhi = min(63, (x + 1) >> 1);
    float s = 0.f;
    for (int oy = oylo; oy <= oyhi; ++oy)
        for (int ox = oxlo; ox <= oxhi; ++ox) {
            int kd = y - 2 * oy + 1;
            int ke = x - 2 * ox + 1;
            s += C2t[(size_t)(c * 16 + kd * 4 + ke) * LTOT + oy * 64 + ox];
        }
    out[idx] = s * 0.25f;
}

extern "C" void kernel_launch(void* const* d_in, const int* in_sizes, int n_in,
                              void* d_out, int out_size, void* d_ws, size_t ws_size,
                              hipStream_t stream) {
    (void)in_sizes; (void)n_in; (void)out_size; (void)ws_size;
    const float* f    = (const float*)d_in[0];
    const float* b    = (const float*)d_in[1];
    const float* mask = (const float*)d_in[2];
    float* out = (float*)d_out;

    const size_t SZ_MAT = (size_t)LTOT * LTOT * 4;   // 64 MB
    const size_t SZ_WR  = (size_t)K2 * LTOT * 2;     // 16 MB
    const size_t SZ_SP  = (size_t)LTOT * K0S * 2;    // 3 MB
    const size_t SZ_V   = (size_t)LTOT * 4;

    auto pad = [](size_t n) { return (n + 255) & ~(size_t)255; };
    char* p = (char*)d_ws;
    auto take = [&](size_t n) -> void* { void* r = (void*)p; p += pad(n); return r; };

    // footprint: 64 + 64 + 16 + 16 + 4*3 + small ~= 172 MB (proven-safe)
    float* Buf1 = (float*)take(SZ_MAT);   // Cpix -> S16 (lower 32 MB)
    float* Buf2 = (float*)take(SZ_MAT);   // Sp   -> C2t (lower 32 MB)
    unsigned short* W0 = (unsigned short*)take(SZ_WR);
    unsigned short* W1 = (unsigned short*)take(SZ_WR);
    unsigned short* Bsp0 = (unsigned short*)take(SZ_SP);
    unsigned short* Fsp0 = (unsigned short*)take(SZ_SP);
    unsigned short* Bsp1 = (unsigned short*)take(SZ_SP);
    unsigned short* Fsp1 = (unsigned short*)take(SZ_SP);
    float* ssq0 = (float*)take(SZ_V);  float* ssq1 = (float*)take(SZ_V);
    float* invn0 = (float*)take(SZ_V); float* invn1 = (float*)take(SZ_V);
    float* mmv0 = (float*)take(SZ_V);  float* mmv1 = (float*)take(SZ_V);

    const float* f0 = f,  *b0 = b;
    const float* f1 = f + IMG, *b1 = b + IMG;

    unsigned short* S16 = (unsigned short*)Buf1;   // 32 MB, after Cpix dead
    float* C2t = Buf2;                              // 32 MB, after Sp dead

    // ---- merged prep (both batches); ssq fused into the b split passes ----
    Prep4 P{{b0, f0, b1, f1}, {Bsp0, Fsp0, Bsp1, Fsp1},
            {ssq0, nullptr, ssq1, nullptr}, {1, 0, 1, 0}};
    split_ds_kernel<<<dim3(LTOT, 1, 4), 128, 0, stream>>>(P);
    PtrN2 nm{{ssq0, ssq1}, {invn0, invn1}, {mmv0, mmv1}};
    norm_mm_kernel<<<dim3(16, 1, 2), 256, 0, stream>>>(nm, mask);
    PtrR2 rw{{b0, b1}, {W0, W1}};
    im2col_rawt_kernel<<<dim3((size_t)K2 * LTOT / 256, 1, 2), 256, 0, stream>>>(rw);

    // ---- per-batch pipeline ----
    for (int bi = 0; bi < 2; ++bi) {
        const unsigned short* Fsp = bi ? Fsp1 : Fsp0;
        const unsigned short* Bsp = bi ? Bsp1 : Bsp0;
        const unsigned short* W   = bi ? W1 : W0;
        const float* invn = bi ? invn1 : invn0;
        const float* mmv  = bi ? mmv1 : mmv0;

        // Cpix[q][p] = sum_c fd[c][q]*bd[c][p]   (split-concat fp32-accurate, K=384)
        gemm_mfma<<<dim3(32, 32), 256, 0, stream>>>(Fsp, Bsp, Buf1, LTOT, LTOT, K0S);

        // patch inner products: 9-tap diagonal stencil + invn column scale
        stencil_norm_kernel<<<LTOT, 256, 0, stream>>>(Buf1, invn, Buf2);

        // fused (fuse2 o fuse1) + softmax + bf16 cast  (Cpix dead -> S16 in Buf1 lower half)
        fused_conv_softmax_kernel<<<LTOT, 256, 0, stream>>>(Buf2, mmv, S16);

        // TRANSPOSED GEMM2: C2t[m2][q] = sum_p W[m2][p] * S16[q][p]   (Sp dead -> C2t in Buf2)
        gemm_mfma<<<dim3(LTOT / 128, K2 / 128), 256, 0, stream>>>(W, S16, C2t, K2, LTOT, LTOT);

        output_kernel<<<CC * HH * WW / 256, 256, 0, stream>>>(C2t, out + (size_t)bi * IMG);
    }
}

// Round 2
// 547.296 us; speedup vs baseline: 1.1254x; 1.1254x over previous
//
#include <hip/hip_runtime.h>

#define CC 128
#define HH 128
#define WW 128
#define DH 64
#define DW 64
#define LTOT 4096          // DH*DW patches / fg positions
#define K0S 384            // 3*128 split-concat K for the pixel-pair GEMM
#define K2 2048            // CC*4*4
#define SCALE_F 10.0f
#define IMG ((size_t)CC * HH * WW)
#define PSTR 4104          // padded S row stride (floats): 4 pad | 4096 | 4 pad; %4==0 keeps 16B align

typedef __attribute__((ext_vector_type(8))) short short8;
typedef __attribute__((ext_vector_type(4))) float f32x4;

// ---- pointer-pack structs (batch-merged prep via blockIdx.z) ----
struct Prep4 { const float* src[4]; unsigned short* dst[4]; float* ssq[4]; int lo[4]; };
struct PtrN2 { const float* ssq[2]; float* invn[2]; float* mmv[2]; };
struct PtrR2 { const float* src[2]; unsigned short* dst[2]; };

// ---- bf16 helpers (RNE) ----
__device__ __forceinline__ unsigned short f2bf(float x) {
    union { float f; unsigned u; } v; v.f = x;
    unsigned r = v.u + 0x7fffu + ((v.u >> 16) & 1u);
    return (unsigned short)(r >> 16);
}
__device__ __forceinline__ float bf2f(unsigned short b) {
    union { unsigned u; float f; } v; v.u = ((unsigned)b) << 16;
    return v.f;
}

// unaligned (4B-aligned) float4 load
__device__ __forceinline__ f32x4 ld4u(const float* p) {
    f32x4 r; __builtin_memcpy(&r, p, 16); return r;
}

#define GLDS16(g, l) __builtin_amdgcn_global_load_lds( \
    (const __attribute__((address_space(1))) void*)(g), \
    (__attribute__((address_space(3))) void*)(l), 16, 0, 0)

// ---------------- downsample (::2) + fp32->bf16 split + (for b) fused ssq reduce ----------------
// b gets [hi, lo, hi], f gets [hi, hi, lo]  =>  products sum to hi*hi + lo*hi + hi*lo
__global__ __launch_bounds__(128) void split_ds_kernel(Prep4 P) {
    __shared__ float partial[2];
    int z = blockIdx.z;
    const float* __restrict__ src = P.src[z];
    unsigned short* __restrict__ dst = P.dst[z];
    int lo_in_seg1 = P.lo[z];
    int n = blockIdx.x;          // 4096 pixels
    int c = threadIdx.x;         // 128 channels
    int ny = n >> 6, nx = n & 63;
    float v = src[((size_t)c * HH + 2 * ny) * WW + 2 * nx];
    unsigned short hi = f2bf(v);
    unsigned short lo = f2bf(v - bf2f(hi));
    unsigned short* drow = dst + (size_t)n * K0S;
    drow[c]       = hi;
    drow[128 + c] = lo_in_seg1 ? lo : hi;
    drow[256 + c] = lo_in_seg1 ? hi : lo;

    float* ssq = P.ssq[z];
    if (ssq) {                   // b images only: per-pixel channel sum of squares
        float s2 = v * v;
#pragma unroll
        for (int o = 32; o; o >>= 1) s2 += __shfl_xor(s2, o);
        if ((threadIdx.x & 63) == 0) partial[threadIdx.x >> 6] = s2;
        __syncthreads();
        if (threadIdx.x == 0) ssq[n] = partial[0] + partial[1];
    }
}

// ---------------- raw 4x4 stride-2 patches of full-res b, transposed: dst[m2][p] bf16 ----------------
__global__ __launch_bounds__(256) void im2col_rawt_kernel(PtrR2 P) {
    int z = blockIdx.z;
    const float* __restrict__ src = P.src[z];
    unsigned short* __restrict__ dst = P.dst[z];
    int idx = blockIdx.x * 256 + threadIdx.x;   // K2*LTOT threads, p fastest
    int p = idx & (LTOT - 1);
    int m = idx >> 12;
    int px = p & 63, py = p >> 6;
    int ke = m & 3, kd = (m >> 2) & 3, c = m >> 4;
    int yy = 2 * py - 1 + kd, xx = 2 * px - 1 + ke;
    float v = 0.f;
    if (yy >= 0 && yy < HH && xx >= 0 && xx < WW)
        v = src[((size_t)c * HH + yy) * WW + xx];
    dst[idx] = f2bf(v);
}

// ---------------- patch inverse norm + mask gate ----------------
__global__ void norm_mm_kernel(PtrN2 P, const float* __restrict__ mask) {
    int z = blockIdx.z;
    const float* __restrict__ ssq = P.ssq[z];
    float* __restrict__ inv_norm = P.invn[z];
    float* __restrict__ mmv = P.mmv[z];
    int p = blockIdx.x * blockDim.x + threadIdx.x;     // 4096
    int px = p & 63, py = p >> 6;
    float s = 0.f, ms = 0.f;
    for (int di = -1; di <= 1; ++di)
        for (int dj = -1; dj <= 1; ++dj) {
            int y = py + di, x = px + dj;
            if (y >= 0 && y < DH && x >= 0 && x < DW) {
                s += ssq[y * 64 + x];
                ms += mask[(size_t)(2 * y) * WW + 2 * x];
            }
        }
    float n = sqrtf(s);
    if (n < 1e-4f) n = 1e-4f;
    inv_norm[p] = 1.f / n;
    mmv[p] = (ms == 0.f) ? 1.f : 0.f;
}

// ---------------- bf16 MFMA GEMM, BK=64, hoisted running pointers, XOR swizzle ----------------
// A[M][K], B[N][K], C[M][N] fp32. 128x128 tile, 4 waves 2x2, each 4x4x(2 k-slab) MFMA 16x16x32.
// LDS rows of 128B = 8 chunks of 16B; chunk slot s of row m holds global chunk s ^ (m&7).
__global__ __launch_bounds__(256) void gemm_mfma(
    const unsigned short* __restrict__ Aop, const unsigned short* __restrict__ Bop,
    float* __restrict__ C, int M, int N, int K)
{
    __shared__ short As[128 * 64];
    __shared__ short Bs[128 * 64];
    int tid = threadIdx.x;
    int wave = tid >> 6, lane = tid & 63;
    int wm = (wave >> 1) * 64;
    int wn = (wave & 1) * 64;
    int bm = blockIdx.y * 128, bn = blockIdx.x * 128;

    int rowS = wave * 32;              // wave stages rows [rowS, rowS+32)
    int lrow8 = lane >> 3;             // 0..7 (row within 8-row staging group)
    int gchunk = ((lane & 7) ^ lrow8) * 8;   // swizzled global k-offset (shorts)

    f32x4 acc[4][4] = {};

    int quad = lane >> 4;              // 0..3
    int r16 = lane & 15;
    int pc0 = ((quad)     ^ (r16 & 7)) * 8;  // physical chunk of k-slab 0
    int pc1 = ((4 + quad) ^ (r16 & 7)) * 8;  // physical chunk of k-slab 1

    // hoisted running pointers (k0-invariant base; += 64 shorts per iter)
    const unsigned short* ap0 = Aop + (size_t)(bm + rowS +  0 + lrow8) * K + gchunk;
    const unsigned short* ap1 = Aop + (size_t)(bm + rowS +  8 + lrow8) * K + gchunk;
    const unsigned short* ap2 = Aop + (size_t)(bm + rowS + 16 + lrow8) * K + gchunk;
    const unsigned short* ap3 = Aop + (size_t)(bm + rowS + 24 + lrow8) * K + gchunk;
    const unsigned short* bp0 = Bop + (size_t)(bn + rowS +  0 + lrow8) * K + gchunk;
    const unsigned short* bp1 = Bop + (size_t)(bn + rowS +  8 + lrow8) * K + gchunk;
    const unsigned short* bp2 = Bop + (size_t)(bn + rowS + 16 + lrow8) * K + gchunk;
    const unsigned short* bp3 = Bop + (size_t)(bn + rowS + 24 + lrow8) * K + gchunk;
    short* lA = As + rowS * 64;        // wave-uniform LDS bases
    short* lB = Bs + rowS * 64;

    for (int k0 = 0; k0 < K; k0 += 64) {
        GLDS16(ap0, lA);            GLDS16(ap1, lA + 8 * 64);
        GLDS16(ap2, lA + 16 * 64);  GLDS16(ap3, lA + 24 * 64);
        GLDS16(bp0, lB);            GLDS16(bp1, lB + 8 * 64);
        GLDS16(bp2, lB + 16 * 64);  GLDS16(bp3, lB + 24 * 64);
        ap0 += 64; ap1 += 64; ap2 += 64; ap3 += 64;
        bp0 += 64; bp1 += 64; bp2 += 64; bp3 += 64;
        __syncthreads();

        short8 a0[4], b0[4], a1[4], b1[4];
#pragma unroll
        for (int i = 0; i < 4; ++i) {
            a0[i] = *(const short8*)&As[(wm + i * 16 + r16) * 64 + pc0];
            b0[i] = *(const short8*)&Bs[(wn + i * 16 + r16) * 64 + pc0];
            a1[i] = *(const short8*)&As[(wm + i * 16 + r16) * 64 + pc1];
            b1[i] = *(const short8*)&Bs[(wn + i * 16 + r16) * 64 + pc1];
        }
#pragma unroll
        for (int i = 0; i < 4; ++i)
#pragma unroll
            for (int j = 0; j < 4; ++j) {
                acc[i][j] = __builtin_amdgcn_mfma_f32_16x16x32_bf16(a0[i], b0[j], acc[i][j], 0, 0, 0);
                acc[i][j] = __builtin_amdgcn_mfma_f32_16x16x32_bf16(a1[i], b1[j], acc[i][j], 0, 0, 0);
            }
        __syncthreads();
    }

    int col = lane & 15, rq = (lane >> 4) * 4;
#pragma unroll
    for (int i = 0; i < 4; ++i) {
#pragma unroll
        for (int r = 0; r < 4; ++r) {
            int m = bm + wm + i * 16 + rq + r;
#pragma unroll
            for (int j = 0; j < 4; ++j)
                C[(size_t)m * N + bn + wn + j * 16 + col] = acc[i][j][r];
        }
    }
}

// ---------------- 9-tap patch stencil, VECTORIZED: thread t owns 16 consecutive cols p0=16t ----------------
// Sg points at padded-S row 0, col 0 (row stride PSTR, 4 zero-pad floats each side, 1 zero
// guard row above/below). Per (du,dv) tap: 4 unaligned f32x4 loads; the only per-element
// bound (px+dv in [0,64)) fails for at most one corner element per group -> cndmask to 0.
// Also zeroes this row's col pads; blocks q==0/4095 zero the guard rows.
__global__ __launch_bounds__(256) void stencil_norm_kernel(
    const float* __restrict__ C, const float* __restrict__ invn,
    float* __restrict__ Sg)
{
    int blk = blockIdx.x;
    int q = ((blk & 7) << 9) | (blk >> 3);   // XCD swizzle: contiguous 512-q per XCD
    int t = threadIdx.x;
    int qy = q >> 6, qx = q & 63;
    int chunk = t >> 2;                      // py (uniform over the 16 cols)
    int lanebase = (t & 3) << 4;             // px of first col
    int p0 = t << 4;

    f32x4 acc[4];
#pragma unroll
    for (int g = 0; g < 4; ++g) { acc[g][0] = acc[g][1] = acc[g][2] = acc[g][3] = 0.f; }

#pragma unroll
    for (int du = -1; du <= 1; ++du) {
        if (qy + du < 0 || qy + du > 63) continue;
        if (chunk + du < 0 || chunk + du > 63) continue;   // py+du (uniform)
#pragma unroll
        for (int dv = -1; dv <= 1; ++dv) {
            if (qx + dv < 0 || qx + dv > 63) continue;
            const float* rowp = C + (size_t)(q + 64 * du + dv) * LTOT + 64 * du + dv + p0;
#pragma unroll
            for (int g = 0; g < 4; ++g) {
                f32x4 lv = ld4u(rowp + 4 * g);
                if (dv == -1 && g == 0 && lanebase == 0)  lv[0] = 0.f;  // px+dv = -1
                if (dv ==  1 && g == 3 && lanebase == 48) lv[3] = 0.f;  // px+dv = 64
                acc[g] += lv;
            }
        }
    }
    float* orow = Sg + (size_t)q * PSTR;
#pragma unroll
    for (int g = 0; g < 4; ++g) {
        f32x4 iv = *(const f32x4*)(invn + p0 + 4 * g);
        *(f32x4*)(orow + p0 + 4 * g) = acc[g] * iv;
    }
    // zero this row's column pads (reads touch cols -1 .. 4099)
    if (t == 0) { orow[-4] = orow[-3] = orow[-2] = orow[-1] = 0.f; }
    else if (t == 1) { orow[4096] = orow[4097] = orow[4098] = orow[4099] = 0.f; }
    // zero guard rows -1 and 4096 (full padded rows)
    if (q == 0) {
        float* gr = Sg - 4 - PSTR;
        for (int k = t; k < PSTR; k += 256) gr[k] = 0.f;
    }
    if (q == 4095) {
        float* gr = Sg - 4 + (size_t)4096 * PSTR;
        for (int k = t; k < PSTR; k += 256) gr[k] = 0.f;
    }
}

// ---------------- fused (fuse2 o fuse1) stencil + row softmax + bf16, VECTORIZED ----------------
// R2: R1's LDS vbuf was a NO-OP on VALUBusy (34.5% both) -> the "3x remat" theory was wrong
// (compiler kept v live via AGPR stash at VGPR_Count=24). The 35% VALUBusy is PASS-1 cost:
// ~2300 VALU + 144 scalar gathers/thread from per-ELEMENT swap/bounds/address math.
// Fix: per-16-column vectorization. Within a 16-consecutive-col group the double-swap map
// cc = swap(swap(c)+d2) is affine (cc = ccbase + u) in all three carry cases:
//   interior (0<=chunk+d2<=63): ccbase = (chunk+d2)*64 + lanebase
//   borrow   (chunk=0, d2=-1):  ccbase = 4031 + lanebase   (invalid only c==0   -> t0/j0 mask)
//   carry    (chunk=63, d2=+1): ccbase = lanebase + 1      (invalid only c==4095-> t255/j2 mask)
// d1-taps become rowptr +- (PSTR+1) on the zero-padded S -> branchless. 36 wide loads +
// ~450 VALU/thread (5x cut). v[16] pinned live via empty asm (no remat possible).
__global__ __launch_bounds__(256) void fused_conv_softmax_kernel(
    const float* __restrict__ Sg, const float* __restrict__ mmv,
    unsigned short* __restrict__ S16)
{
    __shared__ float redmax[4];
    __shared__ float redsum[4];
    int blk = blockIdx.x;
    int q = ((blk & 7) << 9) | (blk >> 3);
    int t = threadIdx.x;
    int lane = t & 63, wid = t >> 6;
    int chunk = t >> 2;
    int lanebase = (t & 3) << 4;
    int c0 = t << 4;

    int rbase = ((q & 63) << 6) | (q >> 6);     // swap(q)

    f32x4 sacc[4];
#pragma unroll
    for (int g = 0; g < 4; ++g) { sacc[g][0] = sacc[g][1] = sacc[g][2] = sacc[g][3] = 0.f; }

#pragma unroll
    for (int j = 0; j < 3; ++j) {               // d2 = j-1 (fuse2, flat bounds in swapped space)
        int r2 = rbase + (j - 1);
        if (r2 < 0 || r2 >= LTOT) continue;     // block-uniform
        int rr = ((r2 & 63) << 6) | (r2 >> 6);  // swap(r2)
        int cj = chunk + (j - 1);
        int ccb;
        if (cj < 0)       ccb = 4031 + lanebase;
        else if (cj > 63) ccb = lanebase + 1;
        else              ccb = (cj << 6) + lanebase;
        const float* pr = Sg + (size_t)rr * PSTR + ccb;
#pragma unroll
        for (int g = 0; g < 4; ++g) {
            const float* pg = pr + 4 * g;
            f32x4 lm = ld4u(pg - (PSTR + 1));   // d1 = -1: row rr-1, col cc-1
            f32x4 l0 = ld4u(pg);                // d1 =  0
            f32x4 lp = ld4u(pg + (PSTR + 1));   // d1 = +1
            f32x4 tj = lm + l0 + lp;
            if (j == 0 && g == 0 && t == 0)   tj[0] = 0.f;   // c=0 corner (c2=-1)
            if (j == 2 && g == 3 && t == 255) tj[3] = 0.f;   // c=4095 corner (c2=4096)
            sacc[g] += tj;
        }
    }

    float v[16];
#pragma unroll
    for (int g = 0; g < 4; ++g) {
        f32x4 m4 = *(const f32x4*)(mmv + c0 + 4 * g);
#pragma unroll
        for (int e = 0; e < 4; ++e)
            v[4 * g + e] = sacc[g][e] * m4[e] * SCALE_F;
    }
#pragma unroll
    for (int k = 0; k < 16; ++k) asm volatile("" : "+v"(v[k]));   // pin: no remat of the stencil

    float mx = v[0];
#pragma unroll
    for (int i = 1; i < 16; ++i) mx = fmaxf(mx, v[i]);
#pragma unroll
    for (int o = 32; o; o >>= 1) mx = fmaxf(mx, __shfl_xor(mx, o));
    if (lane == 0) redmax[wid] = mx;
    __syncthreads();
    float gmx = fmaxf(fmaxf(redmax[0], redmax[1]), fmaxf(redmax[2], redmax[3]));

    float s = 0.f;
#pragma unroll
    for (int i = 0; i < 16; ++i) {
        v[i] = __expf(v[i] - gmx);
        s += v[i];
    }
#pragma unroll
    for (int o = 32; o; o >>= 1) s += __shfl_xor(s, o);
    if (lane == 0) redsum[wid] = s;
    __syncthreads();
    float inv = 1.f / (redsum[0] + redsum[1] + redsum[2] + redsum[3]);

    unsigned short* orow = S16 + (size_t)q * LTOT + c0;
    short8 h0, h1;
#pragma unroll
    for (int e = 0; e < 8; ++e) {
        h0[e] = (short)f2bf(v[e]     * inv * mmv[c0 + e]);
        h1[e] = (short)f2bf(v[8 + e] * inv * mmv[c0 + 8 + e]);
    }
    *(short8*)orow = h0;
    *(short8*)(orow + 8) = h1;
}

// ---------------- overlap-add of weighted 4x4 patches (stride 2), /4 ----------------
// C2t is TRANSPOSED: [m2][q] = [(c,kd,ke)][oy*64+ox] -> taps contiguous across threads (x->ox).
__global__ void output_kernel(const float* __restrict__ C2t, float* __restrict__ out) {
    int idx = blockIdx.x * blockDim.x + threadIdx.x;   // CC*HH*WW
    int x = idx & 127;
    int y = (idx >> 7) & 127;
    int c = idx >> 14;
    int oylo = max(0, (y - 1) >> 1), oyhi = min(63, (y + 1) >> 1);
    int oxlo = max(0, (x - 1) >> 1), oxhi = min(63, (x + 1) >> 1);
    float s = 0.f;
    for (int oy = oylo; oy <= oyhi; ++oy)
        for (int ox = oxlo; ox <= oxhi; ++ox) {
            int kd = y - 2 * oy + 1;
            int ke = x - 2 * ox + 1;
            s += C2t[(size_t)(c * 16 + kd * 4 + ke) * LTOT + oy * 64 + ox];
        }
    out[idx] = s * 0.25f;
}

extern "C" void kernel_launch(void* const* d_in, const int* in_sizes, int n_in,
                              void* d_out, int out_size, void* d_ws, size_t ws_size,
                              hipStream_t stream) {
    (void)in_sizes; (void)n_in; (void)out_size; (void)ws_size;
    const float* f    = (const float*)d_in[0];
    const float* b    = (const float*)d_in[1];
    const float* mask = (const float*)d_in[2];
    float* out = (float*)d_out;

    const size_t SZ_MAT  = (size_t)LTOT * LTOT * 4;        // 64 MB
    const size_t SZ_SPAD = (size_t)PSTR * 4098 * 4;        // 67.3 MB padded S (guards + col pads)
    const size_t SZ_WR   = (size_t)K2 * LTOT * 2;          // 16 MB
    const size_t SZ_SP   = (size_t)LTOT * K0S * 2;         // 3 MB
    const size_t SZ_V    = (size_t)LTOT * 4;

    auto pad = [](size_t n) { return (n + 255) & ~(size_t)255; };
    char* p = (char*)d_ws;
    auto take = [&](size_t n) -> void* { void* r = (void*)p; p += pad(n); return r; };

    // footprint: 0.25K guard + 64 + 67.3 + 16 (single W) + 4*3 + small ~= 160 MB (< proven 172)
    take(256);                                     // guard: stencil corner reads C[-1]
    float* Buf1 = (float*)take(SZ_MAT);            // Cpix -> S16 (lower 32 MB)
    float* Spad = (float*)take(SZ_SPAD);           // padded S -> C2t (lower 32 MB)
    unsigned short* W = (unsigned short*)take(SZ_WR);   // per-batch raw patches (im2col in loop)
    unsigned short* Bsp0 = (unsigned short*)take(SZ_SP);
    unsigned short* Fsp0 = (unsigned short*)take(SZ_SP);
    unsigned short* Bsp1 = (unsigned short*)take(SZ_SP);
    unsigned short* Fsp1 = (unsigned short*)take(SZ_SP);
    float* ssq0 = (float*)take(SZ_V);  float* ssq1 = (float*)take(SZ_V);
    float* invn0 = (float*)take(SZ_V); float* invn1 = (float*)take(SZ_V);
    float* mmv0 = (float*)take(SZ_V);  float* mmv1 = (float*)take(SZ_V);

    const float* f0 = f,  *b0 = b;
    const float* f1 = f + IMG, *b1 = b + IMG;

    float* Sg = Spad + PSTR + 4;                   // padded S row 0, col 0
    unsigned short* S16 = (unsigned short*)Buf1;   // 32 MB, after Cpix dead
    float* C2t = Spad;                             // 32 MB, after padded S dead

    // ---- merged prep (both batches); ssq fused into the b split passes ----
    Prep4 P{{b0, f0, b1, f1}, {Bsp0, Fsp0, Bsp1, Fsp1},
            {ssq0, nullptr, ssq1, nullptr}, {1, 0, 1, 0}};
    split_ds_kernel<<<dim3(LTOT, 1, 4), 128, 0, stream>>>(P);
    PtrN2 nm{{ssq0, ssq1}, {invn0, invn1}, {mmv0, mmv1}};
    norm_mm_kernel<<<dim3(16, 1, 2), 256, 0, stream>>>(nm, mask);

    // ---- per-batch pipeline ----
    for (int bi = 0; bi < 2; ++bi) {
        const unsigned short* Fsp = bi ? Fsp1 : Fsp0;
        const unsigned short* Bsp = bi ? Bsp1 : Bsp0;
        const float* invn = bi ? invn1 : invn0;
        const float* mmv  = bi ? mmv1 : mmv0;

        // raw 4x4 patches for this batch only (W reused across batches)
        PtrR2 rw{{bi ? b1 : b0, nullptr}, {W, nullptr}};
        im2col_rawt_kernel<<<dim3((size_t)K2 * LTOT / 256, 1, 1), 256, 0, stream>>>(rw);

        // Cpix[q][p] = sum_c fd[c][q]*bd[c][p]   (split-concat fp32-accurate, K=384)
        gemm_mfma<<<dim3(32, 32), 256, 0, stream>>>(Fsp, Bsp, Buf1, LTOT, LTOT, K0S);

        // patch inner products: 9-tap diagonal stencil + invn column scale -> padded S
        stencil_norm_kernel<<<LTOT, 256, 0, stream>>>(Buf1, invn, Sg);

        // fused (fuse2 o fuse1) + softmax + bf16 cast  (Cpix dead -> S16 in Buf1 lower half)
        fused_conv_softmax_kernel<<<LTOT, 256, 0, stream>>>(Sg, mmv, S16);

        // TRANSPOSED GEMM2: C2t[m2][q] = sum_p W[m2][p] * S16[q][p]   (S dead -> C2t in Spad)
        gemm_mfma<<<dim3(LTOT / 128, K2 / 128), 256, 0, stream>>>(W, S16, C2t, K2, LTOT, LTOT);

        output_kernel<<<CC * HH * WW / 256, 256, 0, stream>>>(C2t, out + (size_t)bi * IMG);
    }
}

// Round 3
// 517.959 us; speedup vs baseline: 1.1892x; 1.0566x over previous
//
#include <hip/hip_runtime.h>

#define CC 128
#define HH 128
#define WW 128
#define DH 64
#define DW 64
#define LTOT 4096          // DH*DW patches / fg positions
#define K0S 384            // 3*128 split-concat K for the pixel-pair GEMM
#define K2 2048            // CC*4*4
#define SCALE_F 10.0f
#define IMG ((size_t)CC * HH * WW)
#define PSTR 4104          // padded S row stride (floats): 4 pad | 4096 | 4 pad; %4==0 keeps 16B align

typedef __attribute__((ext_vector_type(8))) short short8;
typedef __attribute__((ext_vector_type(4))) float f32x4;

// ---- pointer-pack structs (batch-merged prep via blockIdx.z) ----
struct Prep4 { const float* src[4]; unsigned short* dst[4]; float* ssq[4]; int lo[4]; };
struct PtrN2 { const float* ssq[2]; float* invn[2]; float* mmv[2]; };
struct PtrR2 { const float* src[2]; unsigned short* dst[2]; };

// ---- bf16 helpers (RNE) ----
__device__ __forceinline__ unsigned short f2bf(float x) {
    union { float f; unsigned u; } v; v.f = x;
    unsigned r = v.u + 0x7fffu + ((v.u >> 16) & 1u);
    return (unsigned short)(r >> 16);
}
__device__ __forceinline__ float bf2f(unsigned short b) {
    union { unsigned u; float f; } v; v.u = ((unsigned)b) << 16;
    return v.f;
}

// unaligned (4B-aligned) float4 load
__device__ __forceinline__ f32x4 ld4u(const float* p) {
    f32x4 r; __builtin_memcpy(&r, p, 16); return r;
}

#define GLDS16(g, l) __builtin_amdgcn_global_load_lds( \
    (const __attribute__((address_space(1))) void*)(g), \
    (__attribute__((address_space(3))) void*)(l), 16, 0, 0)

// ---------------- downsample (::2) + fp32->bf16 split + (for b) fused ssq reduce ----------------
// b gets [hi, lo, hi], f gets [hi, hi, lo]  =>  products sum to hi*hi + lo*hi + hi*lo
__global__ __launch_bounds__(128) void split_ds_kernel(Prep4 P) {
    __shared__ float partial[2];
    int z = blockIdx.z;
    const float* __restrict__ src = P.src[z];
    unsigned short* __restrict__ dst = P.dst[z];
    int lo_in_seg1 = P.lo[z];
    int n = blockIdx.x;          // 4096 pixels
    int c = threadIdx.x;         // 128 channels
    int ny = n >> 6, nx = n & 63;
    float v = src[((size_t)c * HH + 2 * ny) * WW + 2 * nx];
    unsigned short hi = f2bf(v);
    unsigned short lo = f2bf(v - bf2f(hi));
    unsigned short* drow = dst + (size_t)n * K0S;
    drow[c]       = hi;
    drow[128 + c] = lo_in_seg1 ? lo : hi;
    drow[256 + c] = lo_in_seg1 ? hi : lo;

    float* ssq = P.ssq[z];
    if (ssq) {                   // b images only: per-pixel channel sum of squares
        float s2 = v * v;
#pragma unroll
        for (int o = 32; o; o >>= 1) s2 += __shfl_xor(s2, o);
        if ((threadIdx.x & 63) == 0) partial[threadIdx.x >> 6] = s2;
        __syncthreads();
        if (threadIdx.x == 0) ssq[n] = partial[0] + partial[1];
    }
}

// ---------------- raw 4x4 stride-2 patches of full-res b, transposed: dst[m2][p] bf16 ----------------
__global__ __launch_bounds__(256) void im2col_rawt_kernel(PtrR2 P) {
    int z = blockIdx.z;
    const float* __restrict__ src = P.src[z];
    unsigned short* __restrict__ dst = P.dst[z];
    int idx = blockIdx.x * 256 + threadIdx.x;   // K2*LTOT threads, p fastest
    int p = idx & (LTOT - 1);
    int m = idx >> 12;
    int px = p & 63, py = p >> 6;
    int ke = m & 3, kd = (m >> 2) & 3, c = m >> 4;
    int yy = 2 * py - 1 + kd, xx = 2 * px - 1 + ke;
    float v = 0.f;
    if (yy >= 0 && yy < HH && xx >= 0 && xx < WW)
        v = src[((size_t)c * HH + yy) * WW + xx];
    dst[idx] = f2bf(v);
}

// ---------------- patch inverse norm + mask gate ----------------
__global__ void norm_mm_kernel(PtrN2 P, const float* __restrict__ mask) {
    int z = blockIdx.z;
    const float* __restrict__ ssq = P.ssq[z];
    float* __restrict__ inv_norm = P.invn[z];
    float* __restrict__ mmv = P.mmv[z];
    int p = blockIdx.x * blockDim.x + threadIdx.x;     // 4096
    int px = p & 63, py = p >> 6;
    float s = 0.f, ms = 0.f;
    for (int di = -1; di <= 1; ++di)
        for (int dj = -1; dj <= 1; ++dj) {
            int y = py + di, x = px + dj;
            if (y >= 0 && y < DH && x >= 0 && x < DW) {
                s += ssq[y * 64 + x];
                ms += mask[(size_t)(2 * y) * WW + 2 * x];
            }
        }
    float n = sqrtf(s);
    if (n < 1e-4f) n = 1e-4f;
    inv_norm[p] = 1.f / n;
    mmv[p] = (ms == 0.f) ? 1.f : 0.f;
}

// ---------------- bf16 MFMA GEMM, BK=64, hoisted running pointers, XOR swizzle ----------------
// (kept for GEMM1: M=N=4096, K=384 — short-K, 1024 blocks; not the bottleneck)
__global__ __launch_bounds__(256) void gemm_mfma(
    const unsigned short* __restrict__ Aop, const unsigned short* __restrict__ Bop,
    float* __restrict__ C, int M, int N, int K)
{
    __shared__ short As[128 * 64];
    __shared__ short Bs[128 * 64];
    int tid = threadIdx.x;
    int wave = tid >> 6, lane = tid & 63;
    int wm = (wave >> 1) * 64;
    int wn = (wave & 1) * 64;
    int bm = blockIdx.y * 128, bn = blockIdx.x * 128;

    int rowS = wave * 32;              // wave stages rows [rowS, rowS+32)
    int lrow8 = lane >> 3;             // 0..7 (row within 8-row staging group)
    int gchunk = ((lane & 7) ^ lrow8) * 8;   // swizzled global k-offset (shorts)

    f32x4 acc[4][4] = {};

    int quad = lane >> 4;              // 0..3
    int r16 = lane & 15;
    int pc0 = ((quad)     ^ (r16 & 7)) * 8;  // physical chunk of k-slab 0
    int pc1 = ((4 + quad) ^ (r16 & 7)) * 8;  // physical chunk of k-slab 1

    const unsigned short* ap0 = Aop + (size_t)(bm + rowS +  0 + lrow8) * K + gchunk;
    const unsigned short* ap1 = Aop + (size_t)(bm + rowS +  8 + lrow8) * K + gchunk;
    const unsigned short* ap2 = Aop + (size_t)(bm + rowS + 16 + lrow8) * K + gchunk;
    const unsigned short* ap3 = Aop + (size_t)(bm + rowS + 24 + lrow8) * K + gchunk;
    const unsigned short* bp0 = Bop + (size_t)(bn + rowS +  0 + lrow8) * K + gchunk;
    const unsigned short* bp1 = Bop + (size_t)(bn + rowS +  8 + lrow8) * K + gchunk;
    const unsigned short* bp2 = Bop + (size_t)(bn + rowS + 16 + lrow8) * K + gchunk;
    const unsigned short* bp3 = Bop + (size_t)(bn + rowS + 24 + lrow8) * K + gchunk;
    short* lA = As + rowS * 64;        // wave-uniform LDS bases
    short* lB = Bs + rowS * 64;

    for (int k0 = 0; k0 < K; k0 += 64) {
        GLDS16(ap0, lA);            GLDS16(ap1, lA + 8 * 64);
        GLDS16(ap2, lA + 16 * 64);  GLDS16(ap3, lA + 24 * 64);
        GLDS16(bp0, lB);            GLDS16(bp1, lB + 8 * 64);
        GLDS16(bp2, lB + 16 * 64);  GLDS16(bp3, lB + 24 * 64);
        ap0 += 64; ap1 += 64; ap2 += 64; ap3 += 64;
        bp0 += 64; bp1 += 64; bp2 += 64; bp3 += 64;
        __syncthreads();

        short8 a0[4], b0[4], a1[4], b1[4];
#pragma unroll
        for (int i = 0; i < 4; ++i) {
            a0[i] = *(const short8*)&As[(wm + i * 16 + r16) * 64 + pc0];
            b0[i] = *(const short8*)&Bs[(wn + i * 16 + r16) * 64 + pc0];
            a1[i] = *(const short8*)&As[(wm + i * 16 + r16) * 64 + pc1];
            b1[i] = *(const short8*)&Bs[(wn + i * 16 + r16) * 64 + pc1];
        }
#pragma unroll
        for (int i = 0; i < 4; ++i)
#pragma unroll
            for (int j = 0; j < 4; ++j) {
                acc[i][j] = __builtin_amdgcn_mfma_f32_16x16x32_bf16(a0[i], b0[j], acc[i][j], 0, 0, 0);
                acc[i][j] = __builtin_amdgcn_mfma_f32_16x16x32_bf16(a1[i], b1[j], acc[i][j], 0, 0, 0);
            }
        __syncthreads();
    }

    int col = lane & 15, rq = (lane >> 4) * 4;
#pragma unroll
    for (int i = 0; i < 4; ++i) {
#pragma unroll
        for (int r = 0; r < 4; ++r) {
            int m = bm + wm + i * 16 + rq + r;
#pragma unroll
            for (int j = 0; j < 4; ++j)
                C[(size_t)m * N + bn + wn + j * 16 + col] = acc[i][j][r];
        }
    }
}

// ---------------- GEMM2: 128x256 tile, 8 waves, ring-of-3 LDS, counted vmcnt (T3+T4+T5) ----------------
// R3: GEMM2 (M=2048,N=4096,K=4096) was at the m97-structure ceiling (773 TF, MfmaUtil 32%):
// __syncthreads drains vmcnt(0) every K-step. This kernel: raw s_barrier + hand-counted vmcnt.
// Ring of 3 tile-buffers (48 KB each = A[128][64] + B[256][64] swizzled bf16). Per K-tile T:
//   ds_read ALL frags of tile T -> regs; lgkmcnt(0); sched_barrier(0)  [rule 18]
//   vmcnt(6)   <- retires tile T+1 (this wave's loads); T+2 stays in flight (never 0!)
//   s_barrier  <- makes both "reads done" and "T+1 resident" BLOCK-wide
//   stage tile T+3 into buf(T%3) (just freed by the barrier) : 6 x global_load_lds
//   setprio(1); 32 MFMA; setprio(0)
// Residency chain: iter T's vmcnt+barrier guarantees tile T+1 before iter T+1's ds_reads.
__global__ __launch_bounds__(512, 2) void gemm_ring3(
    const unsigned short* __restrict__ Aop, const unsigned short* __restrict__ Bop,
    float* __restrict__ C, int N)
{
    constexpr int NT = 64;                        // K = 4096 / 64
    constexpr int BUFS = (128 + 256) * 64;        // shorts per ring slot (48 KB)
    __shared__ short lds[3 * BUFS];               // 144 KB
    const int K = NT * 64;
    int tid = threadIdx.x;
    int wave = tid >> 6, lane = tid & 63;
    int wm = (wave >> 2) * 64;                    // 0,64
    int wn = (wave & 3) * 64;                     // 0,64,128,192
    int bm = blockIdx.y * 128, bn = blockIdx.x * 256;
    int lrow8 = lane >> 3;
    int gchunk = ((lane & 7) ^ lrow8) * 8;        // pre-swizzled global k-offset (shorts)
    int r16 = lane & 15, quad = lane >> 4;
    int pc0 = ((quad)     ^ (r16 & 7)) * 8;
    int pc1 = ((4 + quad) ^ (r16 & 7)) * 8;

    // staging: wave w owns A rows [16w,16w+16) (2 glds) and B rows [32w,32w+32) (4 glds)
    const unsigned short* ap0 = Aop + (size_t)(bm + wave * 16 +  0 + lrow8) * K + gchunk;
    const unsigned short* ap1 = Aop + (size_t)(bm + wave * 16 +  8 + lrow8) * K + gchunk;
    const unsigned short* bp0 = Bop + (size_t)(bn + wave * 32 +  0 + lrow8) * K + gchunk;
    const unsigned short* bp1 = Bop + (size_t)(bn + wave * 32 +  8 + lrow8) * K + gchunk;
    const unsigned short* bp2 = Bop + (size_t)(bn + wave * 32 + 16 + lrow8) * K + gchunk;
    const unsigned short* bp3 = Bop + (size_t)(bn + wave * 32 + 24 + lrow8) * K + gchunk;

    f32x4 acc[4][4] = {};

#define STAGE_T(s) do { \
    short* la = lds + (s) * BUFS + (wave * 16) * 64; \
    short* lb = lds + (s) * BUFS + 128 * 64 + (wave * 32) * 64; \
    GLDS16(ap0, la); GLDS16(ap1, la + 8 * 64); \
    GLDS16(bp0, lb); GLDS16(bp1, lb + 8 * 64); \
    GLDS16(bp2, lb + 16 * 64); GLDS16(bp3, lb + 24 * 64); \
    ap0 += 64; ap1 += 64; bp0 += 64; bp1 += 64; bp2 += 64; bp3 += 64; } while (0)

    // prologue: fill the ring (tiles 0,1,2); require tile 0 resident, leave 1,2 in flight
    STAGE_T(0); STAGE_T(1); STAGE_T(2);
    asm volatile("s_waitcnt vmcnt(12)" ::: "memory");
    __builtin_amdgcn_s_barrier();
    asm volatile("" ::: "memory");

    int buf = 0;
#pragma unroll 1
    for (int T = 0; T < NT; ++T) {
        const short* Ab = lds + buf * BUFS;
        const short* Bb = Ab + 128 * 64;
        short8 a0[4], a1[4], b0[4], b1[4];
#pragma unroll
        for (int i = 0; i < 4; ++i) {
            a0[i] = *(const short8*)&Ab[(wm + i * 16 + r16) * 64 + pc0];
            a1[i] = *(const short8*)&Ab[(wm + i * 16 + r16) * 64 + pc1];
            b0[i] = *(const short8*)&Bb[(wn + i * 16 + r16) * 64 + pc0];
            b1[i] = *(const short8*)&Bb[(wn + i * 16 + r16) * 64 + pc1];
        }
        asm volatile("s_waitcnt lgkmcnt(0)" ::: "memory");
        __builtin_amdgcn_sched_barrier(0);
        if (T + 2 < NT) { asm volatile("s_waitcnt vmcnt(6)" ::: "memory"); }
        else            { asm volatile("s_waitcnt vmcnt(0)" ::: "memory"); }
        __builtin_amdgcn_s_barrier();
        asm volatile("" ::: "memory");
        if (T + 3 < NT) STAGE_T(buf);
        __builtin_amdgcn_s_setprio(1);
#pragma unroll
        for (int i = 0; i < 4; ++i)
#pragma unroll
            for (int j = 0; j < 4; ++j) {
                acc[i][j] = __builtin_amdgcn_mfma_f32_16x16x32_bf16(a0[i], b0[j], acc[i][j], 0, 0, 0);
                acc[i][j] = __builtin_amdgcn_mfma_f32_16x16x32_bf16(a1[i], b1[j], acc[i][j], 0, 0, 0);
            }
        __builtin_amdgcn_s_setprio(0);
        buf = (buf == 2) ? 0 : buf + 1;
    }
#undef STAGE_T

    int col = lane & 15, rq = (lane >> 4) * 4;
#pragma unroll
    for (int i = 0; i < 4; ++i) {
#pragma unroll
        for (int r = 0; r < 4; ++r) {
            int m = bm + wm + i * 16 + rq + r;
#pragma unroll
            for (int j = 0; j < 4; ++j)
                C[(size_t)m * N + bn + wn + j * 16 + col] = acc[i][j][r];
        }
    }
}

// ---------------- 9-tap patch stencil, VECTORIZED: thread t owns 16 consecutive cols p0=16t ----------------
__global__ __launch_bounds__(256) void stencil_norm_kernel(
    const float* __restrict__ C, const float* __restrict__ invn,
    float* __restrict__ Sg)
{
    int blk = blockIdx.x;
    int q = ((blk & 7) << 9) | (blk >> 3);   // XCD swizzle: contiguous 512-q per XCD
    int t = threadIdx.x;
    int qy = q >> 6, qx = q & 63;
    int chunk = t >> 2;                      // py (uniform over the 16 cols)
    int lanebase = (t & 3) << 4;             // px of first col
    int p0 = t << 4;

    f32x4 acc[4];
#pragma unroll
    for (int g = 0; g < 4; ++g) { acc[g][0] = acc[g][1] = acc[g][2] = acc[g][3] = 0.f; }

#pragma unroll
    for (int du = -1; du <= 1; ++du) {
        if (qy + du < 0 || qy + du > 63) continue;
        if (chunk + du < 0 || chunk + du > 63) continue;   // py+du (uniform)
#pragma unroll
        for (int dv = -1; dv <= 1; ++dv) {
            if (qx + dv < 0 || qx + dv > 63) continue;
            const float* rowp = C + (size_t)(q + 64 * du + dv) * LTOT + 64 * du + dv + p0;
#pragma unroll
            for (int g = 0; g < 4; ++g) {
                f32x4 lv = ld4u(rowp + 4 * g);
                if (dv == -1 && g == 0 && lanebase == 0)  lv[0] = 0.f;  // px+dv = -1
                if (dv ==  1 && g == 3 && lanebase == 48) lv[3] = 0.f;  // px+dv = 64
                acc[g] += lv;
            }
        }
    }
    float* orow = Sg + (size_t)q * PSTR;
#pragma unroll
    for (int g = 0; g < 4; ++g) {
        f32x4 iv = *(const f32x4*)(invn + p0 + 4 * g);
        *(f32x4*)(orow + p0 + 4 * g) = acc[g] * iv;
    }
    // zero this row's column pads (reads touch cols -1 .. 4099)
    if (t == 0) { orow[-4] = orow[-3] = orow[-2] = orow[-1] = 0.f; }
    else if (t == 1) { orow[4096] = orow[4097] = orow[4098] = orow[4099] = 0.f; }
    // zero guard rows -1 and 4096 (full padded rows)
    if (q == 0) {
        float* gr = Sg - 4 - PSTR;
        for (int k = t; k < PSTR; k += 256) gr[k] = 0.f;
    }
    if (q == 4095) {
        float* gr = Sg - 4 + (size_t)4096 * PSTR;
        for (int k = t; k < PSTR; k += 256) gr[k] = 0.f;
    }
}

// ---------------- fused (fuse2 o fuse1) stencil + row softmax + bf16, VECTORIZED ----------------
__global__ __launch_bounds__(256) void fused_conv_softmax_kernel(
    const float* __restrict__ Sg, const float* __restrict__ mmv,
    unsigned short* __restrict__ S16)
{
    __shared__ float redmax[4];
    __shared__ float redsum[4];
    int blk = blockIdx.x;
    int q = ((blk & 7) << 9) | (blk >> 3);
    int t = threadIdx.x;
    int lane = t & 63, wid = t >> 6;
    int chunk = t >> 2;
    int lanebase = (t & 3) << 4;
    int c0 = t << 4;

    int rbase = ((q & 63) << 6) | (q >> 6);     // swap(q)

    f32x4 sacc[4];
#pragma unroll
    for (int g = 0; g < 4; ++g) { sacc[g][0] = sacc[g][1] = sacc[g][2] = sacc[g][3] = 0.f; }

#pragma unroll
    for (int j = 0; j < 3; ++j) {               // d2 = j-1 (fuse2, flat bounds in swapped space)
        int r2 = rbase + (j - 1);
        if (r2 < 0 || r2 >= LTOT) continue;     // block-uniform
        int rr = ((r2 & 63) << 6) | (r2 >> 6);  // swap(r2)
        int cj = chunk + (j - 1);
        int ccb;
        if (cj < 0)       ccb = 4031 + lanebase;
        else if (cj > 63) ccb = lanebase + 1;
        else              ccb = (cj << 6) + lanebase;
        const float* pr = Sg + (size_t)rr * PSTR + ccb;
#pragma unroll
        for (int g = 0; g < 4; ++g) {
            const float* pg = pr + 4 * g;
            f32x4 lm = ld4u(pg - (PSTR + 1));   // d1 = -1: row rr-1, col cc-1
            f32x4 l0 = ld4u(pg);                // d1 =  0
            f32x4 lp = ld4u(pg + (PSTR + 1));   // d1 = +1
            f32x4 tj = lm + l0 + lp;
            if (j == 0 && g == 0 && t == 0)   tj[0] = 0.f;   // c=0 corner (c2=-1)
            if (j == 2 && g == 3 && t == 255) tj[3] = 0.f;   // c=4095 corner (c2=4096)
            sacc[g] += tj;
        }
    }

    float v[16];
#pragma unroll
    for (int g = 0; g < 4; ++g) {
        f32x4 m4 = *(const f32x4*)(mmv + c0 + 4 * g);
#pragma unroll
        for (int e = 0; e < 4; ++e)
            v[4 * g + e] = sacc[g][e] * m4[e] * SCALE_F;
    }
#pragma unroll
    for (int k = 0; k < 16; ++k) asm volatile("" : "+v"(v[k]));   // pin: no remat of the stencil

    float mx = v[0];
#pragma unroll
    for (int i = 1; i < 16; ++i) mx = fmaxf(mx, v[i]);
#pragma unroll
    for (int o = 32; o; o >>= 1) mx = fmaxf(mx, __shfl_xor(mx, o));
    if (lane == 0) redmax[wid] = mx;
    __syncthreads();
    float gmx = fmaxf(fmaxf(redmax[0], redmax[1]), fmaxf(redmax[2], redmax[3]));

    float s = 0.f;
#pragma unroll
    for (int i = 0; i < 16; ++i) {
        v[i] = __expf(v[i] - gmx);
        s += v[i];
    }
#pragma unroll
    for (int o = 32; o; o >>= 1) s += __shfl_xor(s, o);
    if (lane == 0) redsum[wid] = s;
    __syncthreads();
    float inv = 1.f / (redsum[0] + redsum[1] + redsum[2] + redsum[3]);

    unsigned short* orow = S16 + (size_t)q * LTOT + c0;
    short8 h0, h1;
#pragma unroll
    for (int e = 0; e < 8; ++e) {
        h0[e] = (short)f2bf(v[e]     * inv * mmv[c0 + e]);
        h1[e] = (short)f2bf(v[8 + e] * inv * mmv[c0 + 8 + e]);
    }
    *(short8*)orow = h0;
    *(short8*)(orow + 8) = h1;
}

// ---------------- overlap-add of weighted 4x4 patches (stride 2), /4 ----------------
// C2t is TRANSPOSED: [m2][q] = [(c,kd,ke)][oy*64+ox] -> taps contiguous across threads (x->ox).
__global__ void output_kernel(const float* __restrict__ C2t, float* __restrict__ out) {
    int idx = blockIdx.x * blockDim.x + threadIdx.x;   // CC*HH*WW
    int x = idx & 127;
    int y = (idx >> 7) & 127;
    int c = idx >> 14;
    int oylo = max(0, (y - 1) >> 1), oyhi = min(63, (y + 1) >> 1);
    int oxlo = max(0, (x - 1) >> 1), oxhi = min(63, (x + 1) >> 1);
    float s = 0.f;
    for (int oy = oylo; oy <= oyhi; ++oy)
        for (int ox = oxlo; ox <= oxhi; ++ox) {
            int kd = y - 2 * oy + 1;
            int ke = x - 2 * ox + 1;
            s += C2t[(size_t)(c * 16 + kd * 4 + ke) * LTOT + oy * 64 + ox];
        }
    out[idx] = s * 0.25f;
}

extern "C" void kernel_launch(void* const* d_in, const int* in_sizes, int n_in,
                              void* d_out, int out_size, void* d_ws, size_t ws_size,
                              hipStream_t stream) {
    (void)in_sizes; (void)n_in; (void)out_size; (void)ws_size;
    const float* f    = (const float*)d_in[0];
    const float* b    = (const float*)d_in[1];
    const float* mask = (const float*)d_in[2];
    float* out = (float*)d_out;

    const size_t SZ_MAT  = (size_t)LTOT * LTOT * 4;        // 64 MB
    const size_t SZ_SPAD = (size_t)PSTR * 4098 * 4;        // 67.3 MB padded S (guards + col pads)
    const size_t SZ_WR   = (size_t)K2 * LTOT * 2;          // 16 MB
    const size_t SZ_SP   = (size_t)LTOT * K0S * 2;         // 3 MB
    const size_t SZ_V    = (size_t)LTOT * 4;

    auto pad = [](size_t n) { return (n + 255) & ~(size_t)255; };
    char* p = (char*)d_ws;
    auto take = [&](size_t n) -> void* { void* r = (void*)p; p += pad(n); return r; };

    // footprint: 0.25K guard + 64 + 67.3 + 16 (single W) + 4*3 + small ~= 160 MB (< proven 172)
    take(256);                                     // guard: stencil corner reads C[-1]
    float* Buf1 = (float*)take(SZ_MAT);            // Cpix -> S16 (lower 32 MB)
    float* Spad = (float*)take(SZ_SPAD);           // padded S -> C2t (lower 32 MB)
    unsigned short* W = (unsigned short*)take(SZ_WR);   // per-batch raw patches (im2col in loop)
    unsigned short* Bsp0 = (unsigned short*)take(SZ_SP);
    unsigned short* Fsp0 = (unsigned short*)take(SZ_SP);
    unsigned short* Bsp1 = (unsigned short*)take(SZ_SP);
    unsigned short* Fsp1 = (unsigned short*)take(SZ_SP);
    float* ssq0 = (float*)take(SZ_V);  float* ssq1 = (float*)take(SZ_V);
    float* invn0 = (float*)take(SZ_V); float* invn1 = (float*)take(SZ_V);
    float* mmv0 = (float*)take(SZ_V);  float* mmv1 = (float*)take(SZ_V);

    const float* f0 = f,  *b0 = b;
    const float* f1 = f + IMG, *b1 = b + IMG;

    float* Sg = Spad + PSTR + 4;                   // padded S row 0, col 0
    unsigned short* S16 = (unsigned short*)Buf1;   // 32 MB, after Cpix dead
    float* C2t = Spad;                             // 32 MB, after padded S dead

    // ---- merged prep (both batches); ssq fused into the b split passes ----
    Prep4 P{{b0, f0, b1, f1}, {Bsp0, Fsp0, Bsp1, Fsp1},
            {ssq0, nullptr, ssq1, nullptr}, {1, 0, 1, 0}};
    split_ds_kernel<<<dim3(LTOT, 1, 4), 128, 0, stream>>>(P);
    PtrN2 nm{{ssq0, ssq1}, {invn0, invn1}, {mmv0, mmv1}};
    norm_mm_kernel<<<dim3(16, 1, 2), 256, 0, stream>>>(nm, mask);

    // ---- per-batch pipeline ----
    for (int bi = 0; bi < 2; ++bi) {
        const unsigned short* Fsp = bi ? Fsp1 : Fsp0;
        const unsigned short* Bsp = bi ? Bsp1 : Bsp0;
        const float* invn = bi ? invn1 : invn0;
        const float* mmv  = bi ? mmv1 : mmv0;

        // raw 4x4 patches for this batch only (W reused across batches)
        PtrR2 rw{{bi ? b1 : b0, nullptr}, {W, nullptr}};
        im2col_rawt_kernel<<<dim3((size_t)K2 * LTOT / 256, 1, 1), 256, 0, stream>>>(rw);

        // Cpix[q][p] = sum_c fd[c][q]*bd[c][p]   (split-concat fp32-accurate, K=384)
        gemm_mfma<<<dim3(32, 32), 256, 0, stream>>>(Fsp, Bsp, Buf1, LTOT, LTOT, K0S);

        // patch inner products: 9-tap diagonal stencil + invn column scale -> padded S
        stencil_norm_kernel<<<LTOT, 256, 0, stream>>>(Buf1, invn, Sg);

        // fused (fuse2 o fuse1) + softmax + bf16 cast  (Cpix dead -> S16 in Buf1 lower half)
        fused_conv_softmax_kernel<<<LTOT, 256, 0, stream>>>(Sg, mmv, S16);

        // TRANSPOSED GEMM2 (ring-3 counted-vmcnt): C2t[m2][q] = sum_p W[m2][p] * S16[q][p]
        gemm_ring3<<<dim3(LTOT / 256, K2 / 128), 512, 0, stream>>>(W, S16, C2t, LTOT);

        output_kernel<<<CC * HH * WW / 256, 256, 0, stream>>>(C2t, out + (size_t)bi * IMG);
    }
}